// Round 6
// baseline (181.679 us; speedup 1.0000x reference)
//
#include <hip/hip_runtime.h>

#define TPB 256
#define EPT 4
#define CHUNK (TPB * EPT)   // 1024 elements per block
#define P2T 1024            // single-block fixup kernel
#define NSLICE 64           // histogram slices to spread global atomics

typedef unsigned long long ull;
typedef long long ll;

__device__ __forceinline__ ull shfl_down_u64(ull x, int off) {
    unsigned lo = (unsigned)x, hi = (unsigned)(x >> 32);
    lo = __shfl_down(lo, off, 64);
    hi = __shfl_down(hi, off, 64);
    return ((ull)hi << 32) | lo;
}

// ---------------------------------------------------------------------------
// Pass 1: per-element pre-shift compute + histograms + block sums.
// CHUNK=1024 (EPT=4): 16 blocks/CU -> blocks at mixed phases, cross-block
// memory/VALU overlap; small per-thread state -> early load scheduling.
// Tail: ONE packed u64 atomicAdd into l1sum[b>>5] (fire-and-forget).
// Word: [62:39] = v_sum | [38:0] = combined * 16384 fixed-point.
// ---------------------------------------------------------------------------
__global__ __launch_bounds__(TPB, 8) void k_pass1(
    const float* __restrict__ blp, const int* __restrict__ st,
    const int* __restrict__ q, const int* __restrict__ fam,
    const int* __restrict__ mic, const int* __restrict__ vm,
    float* __restrict__ out_structural,
    int* __restrict__ ghist, ull* __restrict__ l1sum, int n)
{
    __shared__ int lh2[2048];    // [0..1023] q64 x 16 rows | [1024..2047] micro64 x 16 rows
    __shared__ int slhs[11];     // 0-3 fam, 4-10 shell
    __shared__ int swv[4];
    __shared__ float swc[4];

    const int tid = threadIdx.x, lane = tid & 63, wave = tid >> 6;
    const long i0 = (long)blockIdx.x * CHUNK + (long)tid * EPT;
    const bool fast = ((long)(blockIdx.x + 1) * CHUNK <= n);

    // ---- loads first: 6 dwordx4 in flight during LDS init + barrier ----
    int stv[5], qv[5], fv[5], micv[4], vmv[4];
    float bpv[4];
    if (fast) {
        const int4 sa = *(const int4*)(st + i0);
        const int4 qa = *(const int4*)(q + i0);
        const int4 fa = *(const int4*)(fam + i0);
        const int4 ma = *(const int4*)(mic + i0);
        const int4 va = *(const int4*)(vm + i0);
        const float4 ba = *(const float4*)(blp + i0);
        int nst = __shfl_down(sa.x, 1, 64);
        int nq  = __shfl_down(qa.x, 1, 64);
        int nf  = __shfl_down(fa.x, 1, 64);
        if (lane == 63) {                 // next element is outside this wave
            const long j = i0 + 4;
            nst = (j < n) ? st[j]  : 0;
            nq  = (j < n) ? q[j]   : 0;
            nf  = (j < n) ? fam[j] : 0;
        }
        stv[0]=sa.x; stv[1]=sa.y; stv[2]=sa.z; stv[3]=sa.w; stv[4]=nst;
        qv[0]=qa.x;  qv[1]=qa.y;  qv[2]=qa.z;  qv[3]=qa.w;  qv[4]=nq;
        fv[0]=fa.x;  fv[1]=fa.y;  fv[2]=fa.z;  fv[3]=fa.w;  fv[4]=nf;
        micv[0]=ma.x; micv[1]=ma.y; micv[2]=ma.z; micv[3]=ma.w;
        vmv[0]=va.x; vmv[1]=va.y; vmv[2]=va.z; vmv[3]=va.w;
        bpv[0]=ba.x; bpv[1]=ba.y; bpv[2]=ba.z; bpv[3]=ba.w;
    } else {
        #pragma unroll
        for (int e = 0; e < 4; ++e) {
            long ii = i0 + e;
            bool r = ii < n;
            stv[e] = r ? st[ii] : 0;  qv[e] = r ? q[ii] : 0;  fv[e] = r ? fam[ii] : 0;
            micv[e] = r ? mic[ii] : 0; vmv[e] = r ? vm[ii] : 0; bpv[e] = r ? blp[ii] : 0.f;
        }
        stv[4] = (i0 + 4 < n) ? st[i0 + 4] : 0;
        qv[4]  = (i0 + 4 < n) ? q[i0 + 4] : 0;
        fv[4]  = (i0 + 4 < n) ? fam[i0 + 4] : 0;
    }

    {   // vectorized LDS zero-init: 8 ints = 2x ds_write_b128 per thread
        int4 z4; z4.x = 0; z4.y = 0; z4.z = 0; z4.w = 0;
        *(int4*)&lh2[tid * 8] = z4;
        *(int4*)&lh2[tid * 8 + 4] = z4;
    }
    if (tid < 11) slhs[tid] = 0;
    __syncthreads();

    const int qrow = ((wave << 2) | (lane & 3)) << 6;        // 16 sub-rows
    int sv = 0;
    float scf = 0.0f;
    ull accF = 0, accS0 = 0, accS1 = 0;
    float structural[4];
    #pragma unroll
    for (int e = 0; e < 4; ++e) {
        int sti = stv[e], qi = qv[e], fi = fv[e], mi = micv[e];
        int v = (vmv[e] != 0);
        int om  = sti & 0xFFF;      int c6  = ((om  >> 6) ^ om ) & 63;
        int omn = stv[e+1] & 0xFFF; int c6n = ((omn >> 6) ^ omn) & 63;
        float d_chi = (float)__popc(c6 ^ c6n) * (1.0f / 6.0f);
        float d_q   = (float)__popc((qi & 63) ^ (qv[e+1] & 63)) * (1.0f / 6.0f);
        int fx = (fi & 3) ^ (fv[e+1] & 3);
        float d_fam = (float)((fx & 1) + ((fx >> 1) & 1)) * 0.5f;
        float score = 0.5f * d_chi + 0.35f * d_q + 0.15f * d_fam;
        score = fminf(fmaxf(score, 1e-6f), 1.0f);
        structural[e] = v ? score : 0.0f;
        float cosine = expf(fminf(bpv[e], 0.0f));
        float combined = 0.5f * (cosine + structural[e]);
        if (v) {
            sv += 1;
            scf += combined;
            atomicAdd(&lh2[qrow + (qi & 63)], 1);
            atomicAdd(&lh2[1024 + qrow + (mi & 63)], 1);
            accF += 1ULL << ((fi & 3) * 16);
            int sh = __popc(c6);
            ull ts = 1ULL << ((sh & 3) * 16);
            if (sh < 4) accS0 += ts; else accS1 += ts;
        }
    }

    if (fast) {
        float4 o;
        o.x=structural[0]; o.y=structural[1]; o.z=structural[2]; o.w=structural[3];
        *(float4*)(out_structural + i0) = o;
    } else {
        #pragma unroll
        for (int e = 0; e < 4; ++e)
            if (i0 + e < n) out_structural[i0 + e] = structural[e];
    }

    #pragma unroll
    for (int off = 32; off > 0; off >>= 1) {
        sv  += __shfl_down(sv, off, 64);
        scf += __shfl_down(scf, off, 64);
        accF  += shfl_down_u64(accF, off);
        accS0 += shfl_down_u64(accS0, off);
        accS1 += shfl_down_u64(accS1, off);
    }
    if (lane == 0) {
        swv[wave] = sv; swc[wave] = scf;
        #pragma unroll
        for (int b2 = 0; b2 < 4; ++b2) atomicAdd(&slhs[b2],     (int)((accF  >> (16*b2)) & 0xFFFF));
        #pragma unroll
        for (int b2 = 0; b2 < 4; ++b2) atomicAdd(&slhs[4 + b2], (int)((accS0 >> (16*b2)) & 0xFFFF));
        #pragma unroll
        for (int b2 = 0; b2 < 3; ++b2) atomicAdd(&slhs[8 + b2], (int)((accS1 >> (16*b2)) & 0xFFFF));
    }
    __syncthreads();
    if (tid == 0) {
        int vsum = swv[0] + swv[1] + swv[2] + swv[3];
        double cs = (double)swc[0] + (double)swc[1] + (double)swc[2] + (double)swc[3];
        ll cf = (ll)(cs * 16384.0 + 0.5);
        atomicAdd(&l1sum[blockIdx.x >> 5], ((ull)(unsigned)vsum << 39) | (ull)cf);
    }
    // merge bins 0..138 (139..151 derived in pass3 from q_hist64)
    if (tid < 139) {
        const int t2 = tid;
        int val;
        if (t2 < 64) {
            val = 0;
            #pragma unroll
            for (int r = 0; r < 16; ++r) val += lh2[(r << 6) + t2];
        } else if (t2 < 68) {
            val = slhs[t2 - 64];
        } else if (t2 < 132) {
            int b2 = t2 - 68;
            val = 0;
            #pragma unroll
            for (int r = 0; r < 16; ++r) val += lh2[1024 + (r << 6) + b2];
        } else {
            val = slhs[4 + (t2 - 132)];
        }
        if (val) atomicAdd(&ghist[(blockIdx.x & (NSLICE - 1)) * 152 + t2], val);
    }
}

// ---------------------------------------------------------------------------
// Pass 3: prologue (wave 0) reduces the 128 l1sum cells -> shift (2 coalesced
// wave-loads). Algebraic sigmoid p/(p+K(1-p)). Positions kept LOCAL to the
// chunk; pass4 rebuilds global positions from chunk_vsum and fixes the first
// boundary per chunk. Block 0 finalizes the 152-bin histogram.
// ---------------------------------------------------------------------------
__global__ __launch_bounds__(TPB, 8) void k_pass3(
    const float* __restrict__ strc, const float* __restrict__ blp,
    const ull* __restrict__ l1sum, const int* __restrict__ ghist,
    float* __restrict__ out_logp, float* __restrict__ out_bmask,
    float* __restrict__ out_len, int* __restrict__ chunk_cnt,
    int* __restrict__ chunk_lastloc, ull* __restrict__ chunk_first,
    int* __restrict__ chunk_vsum, float* __restrict__ out_hist, int n)
{
    __shared__ int swt[4], swm[4], scnt[4];
    __shared__ ull sfirst[4];
    __shared__ float sShift;
    __shared__ int qh[64];
    const int tid = threadIdx.x, lane = tid & 63, wave = tid >> 6;
    const long i0 = (long)blockIdx.x * CHUNK + (long)tid * EPT;
    const bool fast = ((long)(blockIdx.x + 1) * CHUNK <= n);
    const int nb = (int)gridDim.x;

    // ---- main loads issued first; prologue hides under their latency ----
    float sv4[4], bp4[4];
    if (fast) {
        const float4 s0 = *(const float4*)(strc + i0);
        const float4 p0 = *(const float4*)(blp + i0);
        sv4[0]=s0.x; sv4[1]=s0.y; sv4[2]=s0.z; sv4[3]=s0.w;
        bp4[0]=p0.x; bp4[1]=p0.y; bp4[2]=p0.z; bp4[3]=p0.w;
    } else {
        #pragma unroll
        for (int e = 0; e < 4; ++e) {
            long ii = i0 + e;
            bool r = ii < n;
            sv4[e] = r ? strc[ii] : 0.0f;
            bp4[e] = r ? blp[ii] : 0.0f;
        }
    }

    // ---- prologue: wave 0 reduces 128 group cells -> shift ----
    if (wave == 0) {
        const int ngrp = (nb + 31) >> 5;           // 128 for nb=4096
        int vt = 0; ll ct = 0;
        for (int gg = lane; gg < ngrp; gg += 64) {
            ull cell = l1sum[gg];
            vt += (int)(cell >> 39);
            ct += (ll)(cell & ((1ULL << 39) - 1));
        }
        #pragma unroll
        for (int off = 32; off > 0; off >>= 1) {
            vt += __shfl_down(vt, off, 64);
            ct += (ll)shfl_down_u64((ull)ct, off);
        }
        if (lane == 0) {
            double vcd = (double)(vt > 1 ? vt : 1);
            float cur = (float)(((double)ct * (1.0 / 16384.0)) / vcd);
            cur = fminf(fmaxf(cur, 1e-4f), 0.9999f);
            float p = fminf(fmaxf(cur, 1e-6f), 0.999999f);
            float lc = logf(p) - log1pf(-p);
            float tgt = (float)(1.0 / 6.0);
            float lt = logf(tgt) - log1pf(-tgt);
            sShift = lt - lc;
        }
    }
    __syncthreads();
    const float K = expf(-sShift);

    unsigned mv = 0, mb = 0;
    float lp[4], bmf[4], lenv[4];
    #pragma unroll
    for (int e = 0; e < 4; ++e) {
        float s = sv4[e];
        int v = (s > 0.0f);                  // structural clipped >= 1e-6 iff valid
        float cosine = expf(fminf(bp4[e], 0.0f));
        float comb = 0.5f * (cosine + s);
        float p = fminf(fmaxf(comb, 1e-6f), 0.999999f);
        float d = fmaf(K, 1.0f - p, p);      // p + K(1-p)
        float sgm = p / d;                   // == sigmoid(logit(p)+shift)
        sgm = fminf(fmaxf(sgm, 1e-6f), 0.999999f);
        float clp = logf(sgm);
        lp[e] = clp;
        int bm = (clp >= -0.69314718f) ? 1 : 0;
        bmf[e] = (float)bm;
        mv |= (unsigned)v << e;
        if (bm & v) mb |= 1u << e;
        lenv[e] = 0.0f;
    }
    if (fast) {
        float4 o;
        o.x=lp[0]; o.y=lp[1]; o.z=lp[2]; o.w=lp[3];     *(float4*)(out_logp + i0) = o;
        o.x=bmf[0]; o.y=bmf[1]; o.z=bmf[2]; o.w=bmf[3]; *(float4*)(out_bmask + i0) = o;
    } else {
        #pragma unroll
        for (int e = 0; e < 4; ++e)
            if (i0 + e < n) { out_logp[i0 + e] = lp[e]; out_bmask[i0 + e] = bmf[e]; }
    }

    // block-wide exclusive valid-count prefix (LOCAL: starts at 0)
    int tvc = __popc(mv);
    int x = tvc;
    #pragma unroll
    for (int off = 1; off < 64; off <<= 1) {
        int y = __shfl_up(x, off, 64);
        if (lane >= off) x += y;
    }
    if (lane == 63) swt[wave] = x;
    __syncthreads();
    int wb = 0;
    for (int w2 = 0; w2 < wave; ++w2) wb += swt[w2];
    const int vbase = wb + (x - tvc);          // local (0-based exclusive)

    // last-boundary max-scan + cnt/first reductions (local positions)
    int last = -1;
    if (mb) {
        int hb = 31 - __clz(mb);
        last = vbase + __popc(mv & ((2u << hb) - 1));
    }
    int m = last;
    #pragma unroll
    for (int off = 1; off < 64; off <<= 1) {
        int y = __shfl_up(m, off, 64);
        if (lane >= off && y > m) m = y;
    }
    int exm = __shfl_up(m, 1, 64);
    if (lane == 0) exm = -1;
    if (lane == 63) swm[wave] = m;
    int cnt = __popc(mb);
    ull fp = ~0ULL;
    if (mb) {
        int lb = __ffs(mb) - 1;
        int fv2 = vbase + __popc(mv & ((2u << lb) - 1));   // local 1-indexed
        fp = ((ull)(unsigned)(i0 + lb) << 32) | (unsigned)fv2;
    }
    #pragma unroll
    for (int off = 32; off > 0; off >>= 1) {
        cnt += __shfl_down(cnt, off, 64);
        ull fo = shfl_down_u64(fp, off);
        if (fo < fp) fp = fo;
    }
    if (lane == 0) { scnt[wave] = cnt; sfirst[wave] = fp; }
    __syncthreads();

    int prev = exm;
    for (int w2 = 0; w2 < wave; ++w2) if (swm[w2] > prev) prev = swm[w2];
    int runv = 0;
    #pragma unroll
    for (int e = 0; e < 4; ++e) {
        runv += (mv >> e) & 1;
        if ((mb >> e) & 1) {
            int pos = vbase + runv;
            lenv[e] = (prev >= 0) ? (float)(pos - prev) : 0.0f;  // first-in-chunk fixed by pass4
            prev = pos;
        }
    }
    if (fast) {
        float4 o;
        o.x=lenv[0]; o.y=lenv[1]; o.z=lenv[2]; o.w=lenv[3]; *(float4*)(out_len + i0) = o;
    } else {
        #pragma unroll
        for (int e = 0; e < 4; ++e)
            if (i0 + e < n) out_len[i0 + e] = lenv[e];
    }
    if (tid == 0) {
        int c = scnt[0] + scnt[1] + scnt[2] + scnt[3];
        int L = swm[0];
        if (swm[1] > L) L = swm[1];
        if (swm[2] > L) L = swm[2];
        if (swm[3] > L) L = swm[3];
        ull F = sfirst[0];
        if (sfirst[1] < F) F = sfirst[1];
        if (sfirst[2] < F) F = sfirst[2];
        if (sfirst[3] < F) F = sfirst[3];
        chunk_cnt[blockIdx.x] = c;
        chunk_lastloc[blockIdx.x] = L > 0 ? L : 0;   // local 1-indexed, 0 = none
        chunk_first[blockIdx.x] = F;
        chunk_vsum[blockIdx.x] = swt[0] + swt[1] + swt[2] + swt[3];
    }

    // ---- block 0 free tail: histogram finalize ----
    if (blockIdx.x == 0) {
        if (tid < 139) {
            int acc = 0;
            #pragma unroll 8
            for (int sl = 0; sl < NSLICE; ++sl) acc += ghist[sl * 152 + tid];
            out_hist[tid] = (float)acc;
            if (tid < 64) qh[tid] = acc;
        }
        __syncthreads();
        if (tid < 7) {            // q_weight_hist7[w] = sum over bins with popc==w
            int sacc = 0;
            for (int b = 0; b < 64; ++b) if (__popc(b) == tid) sacc += qh[b];
            out_hist[139 + tid] = (float)sacc;
        }
        if (tid < 6) {            // bit_excitation6[j] = sum qh[b]*bit_j(b)
            int sacc = 0;
            for (int b = 0; b < 64; ++b) sacc += qh[b] * ((b >> tid) & 1);
            out_hist[146 + tid] = (float)sacc;
        }
    }
}

// ---------------------------------------------------------------------------
// Pass 4: rebuild global positions from chunk_vsum (sum-scan), global last
// boundaries (max-scan), first-boundary length fix-up, trailing, patch_count.
// 4 chunks/thread, nb <= 4096.
// ---------------------------------------------------------------------------
__global__ __launch_bounds__(P2T) void k_pass4(
    const int* __restrict__ chunk_cnt, const int* __restrict__ chunk_lastloc,
    const ull* __restrict__ chunk_first, const int* __restrict__ chunk_vsum,
    int nb, float* __restrict__ out_len,
    float* __restrict__ out_trailing, float* __restrict__ out_patch)
{
    __shared__ int ss[P2T];   // sum scan (valid counts)
    __shared__ int sm[P2T];   // max scan (global last boundary)
    __shared__ int sc[P2T];   // count reduce
    const int t = threadIdx.x;
    int v[4], l[4]; ull F[4];
    int vpre[4];
    int vs = 0, ks = 0, rmax = 0;   // rmax: thread-relative max last (0 = none)
    #pragma unroll
    for (int e = 0; e < 4; ++e) {
        int c = t * 4 + e;
        vpre[e] = vs;
        v[e] = (c < nb) ? chunk_vsum[c] : 0;
        l[e] = (c < nb) ? chunk_lastloc[c] : 0;
        int k = (c < nb) ? chunk_cnt[c] : 0;
        F[e] = (c < nb) ? chunk_first[c] : ~0ULL;
        if (l[e] > 0) { int gl = vs + l[e]; if (gl > rmax) rmax = gl; }
        vs += v[e];
        ks += k;
    }
    ss[t] = vs; sc[t] = ks;
    __syncthreads();
    for (int off = 1; off < P2T; off <<= 1) {      // inclusive sum-scan
        int add = (t >= off) ? ss[t - off] : 0;
        __syncthreads();
        ss[t] += add;
        __syncthreads();
    }
    const int base = ss[t] - vs;                   // exclusive valid-prefix
    const int total_v = ss[P2T - 1];
    sm[t] = (rmax > 0) ? base + rmax : 0;          // thread-inclusive global last
    __syncthreads();
    for (int off = 1; off < P2T; off <<= 1) {      // inclusive max-scan
        int y = (t >= off) ? sm[t - off] : 0;
        __syncthreads();
        if (y > sm[t]) sm[t] = y;
        __syncthreads();
    }
    int scarry = (t > 0) ? sm[t - 1] : 0;          // exclusive carry for chunk t*4
    const int gmax = sm[P2T - 1];
    #pragma unroll
    for (int e = 0; e < 4; ++e) {
        if (F[e] != ~0ULL) {
            int fi = (int)(F[e] >> 32);
            int fv = (int)(F[e] & 0xFFFFFFFFu);    // local 1-indexed
            out_len[fi] = (float)(base + vpre[e] + fv - scarry);
        }
        int gl = (l[e] > 0) ? base + vpre[e] + l[e] : 0;
        if (gl > scarry) scarry = gl;
    }
    __syncthreads();
    for (int off = P2T / 2; off > 0; off >>= 1) {  // count reduce
        if (t < off) sc[t] += sc[t + off];
        __syncthreads();
    }
    if (t == 0) {
        int trailing = total_v - gmax;
        *out_trailing = (float)trailing;
        *out_patch = (float)(sc[0] + (trailing > 0 ? 1 : 0));
    }
}

// ---------------------------------------------------------------------------
extern "C" void kernel_launch(void* const* d_in, const int* in_sizes, int n_in,
                              void* d_out, int out_size, void* d_ws, size_t ws_size,
                              hipStream_t stream)
{
    const float* blp = (const float*)d_in[0];
    const int* st   = (const int*)d_in[1];
    const int* q    = (const int*)d_in[2];
    const int* fam  = (const int*)d_in[3];
    const int* mic  = (const int*)d_in[4];
    const int* vm   = (const int*)d_in[5];
    const int n = in_sizes[0];
    const int nb = (n + CHUNK - 1) / CHUNK;          // 4096 for n=4M

    float* out = (float*)d_out;
    float* out_logp       = out;
    float* out_bmask      = out + (size_t)n;
    float* out_structural = out + 2 * (size_t)n;
    float* out_hist       = out + 3 * (size_t)n;     // 152 floats
    float* out_len        = out + 3 * (size_t)n + 152;
    float* out_trailing   = out + 4 * (size_t)n + 152;
    float* out_patch      = out + 4 * (size_t)n + 153;

    char* w = (char*)d_ws;
    int*  ghist         = (int*)(w);                 // 64 x 152 ints   [memset]
    ull*  l1sum         = (ull*)(w + 38912);         // 128 u64         [memset]
    int*  chunk_cnt     = (int*)(w + 40960);         // nb ints (16 KB)
    int*  chunk_lastloc = (int*)(w + 57344);         // nb ints
    int*  chunk_vsum    = (int*)(w + 73728);         // nb ints
    ull*  chunk_first   = (ull*)(w + 90112);         // nb u64 (32 KB) -> end 122880

    hipMemsetAsync(w, 0, 39936, stream);             // ghist + l1sum

    k_pass1<<<dim3(nb), dim3(TPB), 0, stream>>>(
        blp, st, q, fam, mic, vm, out_structural, ghist, l1sum, n);

    k_pass3<<<dim3(nb), dim3(TPB), 0, stream>>>(
        out_structural, blp, l1sum, ghist,
        out_logp, out_bmask, out_len, chunk_cnt, chunk_lastloc, chunk_first,
        chunk_vsum, out_hist, n);

    k_pass4<<<dim3(1), dim3(P2T), 0, stream>>>(
        chunk_cnt, chunk_lastloc, chunk_first, chunk_vsum, nb, out_len,
        out_trailing, out_patch);
}